// Round 11
// baseline (180.285 us; speedup 1.0000x reference)
//
#include <hip/hip_runtime.h>

#define B_    16
#define T_    4096
#define D_    1024
#define CD_   8
#define CS_   1024
#define NROWS 65536
#define EPSF  1e-12f

// ---- d_out float offsets ----
#define OUT_OFF    0
#define COMMIT_OFF 67108864
#define CBLOSS_OFF 67108880
#define IDX_OFF    67108896
#define ZE_OFF     67174432

// ---- ws float offsets ----
#define WS_INWT 0
#define WS_CBR  8192
#define WS_OUTW 16384
#define WS_CN2  24576
#define WS_IDX  25600

template <int CTRL>
static __device__ __forceinline__ float dpp_add(float x) {
    int xi = __builtin_bit_cast(int, x);
    int yi = __builtin_amdgcn_update_dpp(xi, xi, CTRL, 0xF, 0xF, false);
    return x + __builtin_bit_cast(float, yi);
}

// ---------------------------------------------------------------------------
// Prep, 24 blocks x 256 (verbatim)
// ---------------------------------------------------------------------------
__global__ __launch_bounds__(256)
void vq_prep(const float* __restrict__ in_v, const float* __restrict__ in_g,
             const float* __restrict__ out_v, const float* __restrict__ out_g,
             const float* __restrict__ cb, float* __restrict__ ws,
             float* __restrict__ dout) {
    int t = threadIdx.x;
    int blk = blockIdx.x;

    if (blk < 16) {
        __shared__ float s_norm[CD_];
        int lane = t & 63;
        int wid = t >> 6;
        #pragma unroll
        for (int half = 0; half < 2; ++half) {
            int c = wid + half * 4;
            float s = 0.f;
            #pragma unroll
            for (int i = 0; i < D_ / 64; ++i) {
                float v = in_v[(size_t)(lane + 64 * i) * CD_ + c];
                s = fmaf(v, v, s);
            }
            #pragma unroll
            for (int m = 1; m <= 32; m <<= 1) s += __shfl_xor(s, m, 64);
            if (lane == 0) s_norm[c] = sqrtf(s);
        }
        __syncthreads();

        #pragma unroll
        for (int rep = 0; rep < 2; ++rep) {
            int idx = blk * 512 + rep * 256 + t;
            int c = idx >> 10, d = idx & (D_ - 1);
            ws[WS_INWT + idx] = in_g[c] * in_v[(size_t)d * CD_ + c] / fmaxf(EPSF, s_norm[c]);
        }

        if (blk == 0 && t < 32) dout[COMMIT_OFF + t] = 0.f;
    } else if (blk < 20) {
        int j = (blk - 16) * 256 + t;
        float v[CD_]; float s = 0.f;
        #pragma unroll
        for (int c = 0; c < CD_; ++c) { v[c] = cb[j * CD_ + c]; s = fmaf(v[c], v[c], s); }
        float n = fmaxf(EPSF, sqrtf(s));
        float n2 = 0.f;
        #pragma unroll
        for (int c = 0; c < CD_; ++c) {
            float q = v[c] / n;
            ws[WS_CBR + j * CD_ + c] = q;
            n2 = fmaf(q, q, n2);
        }
        ws[WS_CN2 + j] = n2;
    } else {
        int d = (blk - 20) * 256 + t;
        float v[CD_]; float s = 0.f;
        #pragma unroll
        for (int c = 0; c < CD_; ++c) { v[c] = out_v[c * D_ + d]; s = fmaf(v[c], v[c], s); }
        float n = fmaxf(EPSF, sqrtf(s));
        float g = out_g[d];
        #pragma unroll
        for (int c = 0; c < CD_; ++c) ws[WS_OUTW + c * D_ + d] = g * v[c] / n;
    }
}

// ---------------------------------------------------------------------------
// Stage 1: z_e GEMV with explicit 2-deep software pipeline: iteration i+1's
// 8 global loads are issued BEFORE iteration i's FMA/reduce/store. Two static
// register sets (zc/zn); FP sequence identical to R9 (bit-exact z_e).
// ---------------------------------------------------------------------------
__global__ __launch_bounds__(256)
void vq_ze(const float* __restrict__ z, const float* __restrict__ in_b,
           const float* __restrict__ ws, float* __restrict__ dout) {
    __shared__ float lds[CD_ * D_];  // in_wT, 32 KB
    int t = threadIdx.x;
    #pragma unroll
    for (int i = 0; i < 8; ++i)
        ((float4*)lds)[i * 256 + t] = ((const float4*)ws)[i * 256 + t];
    __syncthreads();

    int lane = t & 63;
    int wv = (blockIdx.x << 2) + (t >> 6);  // 0..8191

    float bia[CD_];
    #pragma unroll
    for (int c = 0; c < CD_; ++c) bia[c] = in_b[c];

    const float* zp = z + (lane << 2);

    // ---- preload iteration 0 (rows wv*2, wv*2+1) ----
    float4 zc[8];
    {
        int row0 = wv << 1;
        #pragma unroll
        for (int k = 0; k < 4; ++k) {
            zc[k]     = *(const float4*)(zp + (size_t)(row0)     * D_ + (k << 8));
            zc[4 + k] = *(const float4*)(zp + (size_t)(row0 + 1) * D_ + (k << 8));
        }
    }

    #pragma unroll
    for (int it = 0; it < 4; ++it) {
        int bi = wv + (it << 13);   // 0..32767
        int row0 = bi << 1;

        // ---- issue NEXT iteration's loads first (hide HBM under compute) ----
        float4 zn[8];
        if (it < 3) {
            int nrow0 = (bi + 8192) << 1;
            #pragma unroll
            for (int k = 0; k < 4; ++k) {
                zn[k]     = *(const float4*)(zp + (size_t)(nrow0)     * D_ + (k << 8));
                zn[4 + k] = *(const float4*)(zp + (size_t)(nrow0 + 1) * D_ + (k << 8));
            }
        }

        // ---- FMA phase (R9-identical ordering) ----
        float ze[2][CD_];
        #pragma unroll
        for (int r = 0; r < 2; ++r)
            #pragma unroll
            for (int c = 0; c < CD_; ++c) ze[r][c] = 0.f;

        #pragma unroll
        for (int k = 0; k < 4; ++k) {
            #pragma unroll
            for (int c = 0; c < CD_; ++c) {
                float4 w4 = *(const float4*)(lds + c * D_ + (k << 8) + (lane << 2));
                ze[0][c] = fmaf(zc[k].x,     w4.x, ze[0][c]);
                ze[0][c] = fmaf(zc[k].y,     w4.y, ze[0][c]);
                ze[0][c] = fmaf(zc[k].z,     w4.z, ze[0][c]);
                ze[0][c] = fmaf(zc[k].w,     w4.w, ze[0][c]);
                ze[1][c] = fmaf(zc[4 + k].x, w4.x, ze[1][c]);
                ze[1][c] = fmaf(zc[4 + k].y, w4.y, ze[1][c]);
                ze[1][c] = fmaf(zc[4 + k].z, w4.z, ze[1][c]);
                ze[1][c] = fmaf(zc[4 + k].w, w4.w, ze[1][c]);
            }
        }

        // ---- reduce (R9-identical: 4 DPP + 2 shuffles) ----
        #pragma unroll
        for (int r = 0; r < 2; ++r) {
            #pragma unroll
            for (int c = 0; c < CD_; ++c) {
                float v = ze[r][c];
                v = dpp_add<0xB1>(v);    // + lane^1
                v = dpp_add<0x4E>(v);    // + lane^2
                v = dpp_add<0x124>(v);   // + lane+4 (row_ror:4)
                v = dpp_add<0x128>(v);   // + lane+8 (row_ror:8)
                v += __shfl_xor(v, 16, 64);
                v += __shfl_xor(v, 32, 64);
                ze[r][c] = v + bia[c];
            }
        }

        if (lane == 0) {
            *(float4*)(dout + ZE_OFF + (size_t)row0 * CD_) =
                make_float4(ze[0][0], ze[0][1], ze[0][2], ze[0][3]);
            *(float4*)(dout + ZE_OFF + (size_t)row0 * CD_ + 4) =
                make_float4(ze[0][4], ze[0][5], ze[0][6], ze[0][7]);
        }
        if (lane == 1) {
            *(float4*)(dout + ZE_OFF + (size_t)(row0 + 1) * CD_) =
                make_float4(ze[1][0], ze[1][1], ze[1][2], ze[1][3]);
            *(float4*)(dout + ZE_OFF + (size_t)(row0 + 1) * CD_ + 4) =
                make_float4(ze[1][4], ze[1][5], ze[1][6], ze[1][7]);
        }

        // ---- rotate register sets (renamed away by the compiler) ----
        if (it < 3) {
            #pragma unroll
            for (int i = 0; i < 8; ++i) zc[i] = zn[i];
        }
    }
}

// ---------------------------------------------------------------------------
// Stage 2: scan (R10 verbatim)
// ---------------------------------------------------------------------------
__global__ __launch_bounds__(256)
void vq_scan(const float* __restrict__ ze_in, const float* __restrict__ cb,
             const float* __restrict__ ws, float* __restrict__ dout,
             int* __restrict__ idx_out) {
    __shared__ float s_cb[CS_ * CD_];  // 32 KB
    __shared__ float s_c2[CS_];        // 4 KB
    __shared__ float s_loss[4];
    int t = threadIdx.x;
    #pragma unroll
    for (int i = 0; i < 8; ++i)
        ((float4*)s_cb)[i * 256 + t] = ((const float4*)(ws + WS_CBR))[i * 256 + t];
    ((float4*)s_c2)[t] = ((const float4*)(ws + WS_CN2))[t];
    __syncthreads();

    int lane = t & 63;
    int wid = t >> 6;
    int r = t >> 3;
    int sub = t & 7;
    int row = blockIdx.x * 32 + r;

    float4 a  = *(const float4*)(ze_in + (size_t)row * CD_);
    float4 b4 = *(const float4*)(ze_in + (size_t)row * CD_ + 4);

    float s = 0.f;
    s = fmaf(a.x, a.x, s);   s = fmaf(a.y, a.y, s);
    s = fmaf(a.z, a.z, s);   s = fmaf(a.w, a.w, s);
    s = fmaf(b4.x, b4.x, s); s = fmaf(b4.y, b4.y, s);
    s = fmaf(b4.z, b4.z, s); s = fmaf(b4.w, b4.w, s);
    float tw = 2.f / fmaxf(EPSF, sqrtf(s));

    float bs = -1e38f;
    int bj = 0;
    #pragma unroll 4
    for (int jj = 0; jj < 128; ++jj) {
        int j = (jj << 3) + sub;
        float4 ca  = ((const float4*)s_cb)[j * 2];
        float4 cbv = ((const float4*)s_cb)[j * 2 + 1];
        float2 dp = make_float2(0.f, 0.f);
        dp.x = fmaf(ca.x,  a.x,  dp.x);
        dp.y = fmaf(ca.y,  a.y,  dp.y);
        dp.x = fmaf(ca.z,  a.z,  dp.x);
        dp.y = fmaf(ca.w,  a.w,  dp.y);
        dp.x = fmaf(cbv.x, b4.x, dp.x);
        dp.y = fmaf(cbv.y, b4.y, dp.y);
        dp.x = fmaf(cbv.z, b4.z, dp.x);
        dp.y = fmaf(cbv.w, b4.w, dp.y);
        float dot = dp.x + dp.y;
        float sc = fmaf(dot, tw, -s_c2[j]);
        if (sc > bs || (sc == bs && j < bj)) { bs = sc; bj = j; }
    }
    #pragma unroll
    for (int m = 1; m <= 4; m <<= 1) {
        float os = __shfl_xor(bs, m, 64);
        int   oj = __shfl_xor(bj, m, 64);
        bool take = (os > bs) || (os == bs && oj < bj);
        bs = take ? os : bs;
        bj = take ? oj : bj;
    }

    float lsum = 0.f;
    if (sub == 0) {
        const float* q = cb + (size_t)bj * CD_;
        float d0 = a.x  - q[0]; lsum = fmaf(d0, d0, lsum);
        float d1 = a.y  - q[1]; lsum = fmaf(d1, d1, lsum);
        float d2 = a.z  - q[2]; lsum = fmaf(d2, d2, lsum);
        float d3 = a.w  - q[3]; lsum = fmaf(d3, d3, lsum);
        float d4 = b4.x - q[4]; lsum = fmaf(d4, d4, lsum);
        float d5 = b4.y - q[5]; lsum = fmaf(d5, d5, lsum);
        float d6 = b4.z - q[6]; lsum = fmaf(d6, d6, lsum);
        float d7 = b4.w - q[7]; lsum = fmaf(d7, d7, lsum);
    }
    lsum += __shfl_xor(lsum, 1, 64);
    lsum += __shfl_xor(lsum, 2, 64);
    lsum += __shfl_xor(lsum, 4, 64);
    lsum += __shfl_xor(lsum, 8, 64);
    lsum += __shfl_xor(lsum, 16, 64);
    lsum += __shfl_xor(lsum, 32, 64);
    if (lane == 0) s_loss[wid] = lsum;

    if (sub == 0) {
        dout[IDX_OFF + row] = (float)bj;
        idx_out[row] = bj;
    }
    __syncthreads();
    if (t == 0) {
        float tot = s_loss[0] + s_loss[1] + s_loss[2] + s_loss[3];
        float v = tot * (1.f / 32768.f);
        int bt = row >> 12;
        atomicAdd(dout + COMMIT_OFF + bt, v);
        atomicAdd(dout + CBLOSS_OFF + bt, v);
    }
}

// ---------------------------------------------------------------------------
// Out projection (verbatim)
// ---------------------------------------------------------------------------
__global__ __launch_bounds__(256)
void vq_out(const float* __restrict__ cb, const float* __restrict__ ws,
            const float* __restrict__ out_b, const int* __restrict__ idx,
            float* __restrict__ out) {
    int t = threadIdx.x;
    int lane = t & 63;
    int wv = (blockIdx.x << 2) + (t >> 6);
    const float* ow = ws + WS_OUTW;

    float4 ob[4];
    #pragma unroll
    for (int k = 0; k < 4; ++k)
        ob[k] = *(const float4*)(out_b + (k << 8) + (lane << 2));

    for (int it = 0; it < 4; ++it) {
        int bi = wv + (it << 12);
        int row0 = bi << 2;

        float zq[4][CD_];
        #pragma unroll
        for (int r = 0; r < 4; ++r) {
            int j = idx[row0 + r];
            #pragma unroll
            for (int c = 0; c < CD_; ++c) zq[r][c] = cb[j * CD_ + c];
        }

        #pragma unroll
        for (int k = 0; k < 4; ++k) {
            float4 a0 = ob[k], a1 = ob[k], a2 = ob[k], a3 = ob[k];
            #pragma unroll
            for (int c = 0; c < CD_; ++c) {
                float4 w4 = *(const float4*)(ow + c * D_ + (k << 8) + (lane << 2));
                a0.x = fmaf(zq[0][c], w4.x, a0.x); a0.y = fmaf(zq[0][c], w4.y, a0.y);
                a0.z = fmaf(zq[0][c], w4.z, a0.z); a0.w = fmaf(zq[0][c], w4.w, a0.w);
                a1.x = fmaf(zq[1][c], w4.x, a1.x); a1.y = fmaf(zq[1][c], w4.y, a1.y);
                a1.z = fmaf(zq[1][c], w4.z, a1.z); a1.w = fmaf(zq[1][c], w4.w, a1.w);
                a2.x = fmaf(zq[2][c], w4.x, a2.x); a2.y = fmaf(zq[2][c], w4.y, a2.y);
                a2.z = fmaf(zq[2][c], w4.z, a2.z); a2.w = fmaf(zq[2][c], w4.w, a2.w);
                a3.x = fmaf(zq[3][c], w4.x, a3.x); a3.y = fmaf(zq[3][c], w4.y, a3.y);
                a3.z = fmaf(zq[3][c], w4.z, a3.z); a3.w = fmaf(zq[3][c], w4.w, a3.w);
            }
            size_t base = (size_t)row0 * D_ + (k << 8) + (lane << 2);
            *(float4*)(out + base)            = a0;
            *(float4*)(out + base + D_)       = a1;
            *(float4*)(out + base + 2 * D_)   = a2;
            *(float4*)(out + base + 3 * D_)   = a3;
        }
    }
}

extern "C" void kernel_launch(void* const* d_in, const int* in_sizes, int n_in,
                              void* d_out, int out_size, void* d_ws, size_t ws_size,
                              hipStream_t stream) {
    const float* z     = (const float*)d_in[0];
    const float* in_v  = (const float*)d_in[1];
    const float* in_g  = (const float*)d_in[2];
    const float* in_b  = (const float*)d_in[3];
    const float* out_v = (const float*)d_in[4];
    const float* out_g = (const float*)d_in[5];
    const float* out_b = (const float*)d_in[6];
    const float* cb    = (const float*)d_in[7];
    float* dout = (float*)d_out;
    float* ws   = (float*)d_ws;
    int* idxp   = (int*)(ws + WS_IDX);

    vq_prep<<<24, 256, 0, stream>>>(in_v, in_g, out_v, out_g, cb, ws, dout);
    vq_ze<<<2048, 256, 0, stream>>>(z, in_b, ws, dout);
    vq_scan<<<2048, 256, 0, stream>>>(dout + ZE_OFF, cb, ws, dout, idxp);
    vq_out<<<1024, 256, 0, stream>>>(cb, ws, out_b, idxp, dout + OUT_OFF);
}